// Round 1
// baseline (2008.405 us; speedup 1.0000x reference)
//
#include <hip/hip_runtime.h>
#include <stdint.h>
#include <stddef.h>

// Problem constants
#define S_LEN 128
#define B_SZ  64
#define V_SZ  32000
#define EH    512
#define EO    512
#define H_SZ  1024
#define O_SZ  1024
#define G3    3072   // 3*H

typedef __attribute__((ext_vector_type(8))) short short8;
typedef __attribute__((ext_vector_type(4))) float floatx4;
typedef __attribute__((ext_vector_type(8))) unsigned short ushortx8;

__device__ __forceinline__ unsigned short f2bf(float f) {
  unsigned u = __builtin_bit_cast(unsigned, f);
  u += 0x7FFFu + ((u >> 16) & 1u);   // round-to-nearest-even
  return (unsigned short)(u >> 16);
}
__device__ __forceinline__ float bf2f(unsigned short h) {
  unsigned u = ((unsigned)h) << 16;
  return __builtin_bit_cast(float, u);
}

__device__ __forceinline__ void gld_lds16(const void* g, void* l) {
  __builtin_amdgcn_global_load_lds((const __attribute__((address_space(1))) void*)g,
                                   (__attribute__((address_space(3))) void*)l, 16, 0, 0);
}

// ---------------------------------------------------------------- converts
__global__ __launch_bounds__(256) void cvt_bf16(const float* __restrict__ in,
                                                unsigned short* __restrict__ out, int n4) {
  int i = blockIdx.x * 256 + threadIdx.x;
  if (i < n4) {
    float4 v = ((const float4*)in)[i];
    ushortx8 dummy; (void)dummy;
    unsigned short o0 = f2bf(v.x), o1 = f2bf(v.y), o2 = f2bf(v.z), o3 = f2bf(v.w);
    ushort4 o; o.x = o0; o.y = o1; o.z = o2; o.w = o3;
    ((ushort4*)out)[i] = o;
  }
}

// ------------------------------------------------- W1 [EH][V] -> W1T bf16 [V][EH]
__global__ __launch_bounds__(256) void transpose_w1_bf16(const float* __restrict__ W1,
                                                         unsigned short* __restrict__ W1T) {
  __shared__ unsigned short tile[64][72];   // [v][e], padded
  int t = threadIdx.x;
  int v0 = blockIdx.x * 64;
  int e0 = blockIdx.y * 64;
  // read 64 e-rows x 64 v-cols, float4 per thread
  for (int i = 0; i < 4; ++i) {
    int e = (t >> 4) + i * 16;
    int v = (t & 15) * 4;
    float4 w = *(const float4*)&W1[(size_t)(e0 + e) * V_SZ + v0 + v];
    tile[v + 0][e] = f2bf(w.x);
    tile[v + 1][e] = f2bf(w.y);
    tile[v + 2][e] = f2bf(w.z);
    tile[v + 3][e] = f2bf(w.w);
  }
  __syncthreads();
  // write W1T rows (v), 8 ushort per thread
  for (int i = 0; i < 2; ++i) {
    int v = (t >> 3) + i * 32;
    int e = (t & 7) * 8;
    ushortx8 o;
    for (int j = 0; j < 8; ++j) o[j] = tile[v][e + j];
    *(ushortx8*)&W1T[(size_t)(v0 + v) * EH + e0 + e] = o;
  }
}

// ------------------------------------------------- gather + b1 + threshold -> emb bf16 [8192][512]
__global__ __launch_bounds__(256) void gather_emb(const int* __restrict__ ids,
                                                  const unsigned short* __restrict__ W1T,
                                                  const float* __restrict__ b1,
                                                  unsigned short* __restrict__ emb) {
  int t = threadIdx.x;
  int tok = blockIdx.x * 4 + (t >> 6);
  int lane = t & 63;
  int id = ids[tok];
  ushortx8 w = *(const ushortx8*)&W1T[(size_t)id * EH + lane * 8];
  float4 blo = *(const float4*)&b1[lane * 8];
  float4 bhi = *(const float4*)&b1[lane * 8 + 4];
  float bv[8] = {blo.x, blo.y, blo.z, blo.w, bhi.x, bhi.y, bhi.z, bhi.w};
  ushortx8 o;
  for (int j = 0; j < 8; ++j) {
    float x = bf2f(w[j]) + bv[j];
    x = (x > 1e-6f) ? x : 0.0f;
    o[j] = f2bf(x);
  }
  *(ushortx8*)&emb[(size_t)tok * EH + lane * 8] = o;
}

// ------------------------------------------------- MFMA GEMM, C = act(A @ B^T + bias)
// A [M][K] bf16 row-major, B [N][K] bf16 row-major (i.e. B^T input), bias[N] fp32.
// 128x128 tile, BK=32, 256 threads (4 waves, 2x2 of 64x64), m97-style staging.
template <int ACT, int OUT_BF16>
__global__ __launch_bounds__(256) void gemm_bt(const unsigned short* __restrict__ A,
                                               const unsigned short* __restrict__ B,
                                               const float* __restrict__ bias,
                                               void* __restrict__ Cout,
                                               int M, int N, int K) {
  __shared__ unsigned short lA[128 * 32];
  __shared__ unsigned short lB[128 * 32];
  int t = threadIdx.x;
  int lane = t & 63;
  int wave = t >> 6;
  int bn = blockIdx.x, bm = blockIdx.y;
  int wm = (wave >> 1) * 64;
  int wn = (wave & 1) * 64;
  floatx4 acc[4][4] = {};

  int arow = t >> 2;          // 0..63
  int acol = (t & 3) * 8;     // element offset into 32-wide K slice

  int ga0 = bm * 128 + arow;       if (ga0 >= M) ga0 = M - 1;
  int ga1 = bm * 128 + arow + 64;  if (ga1 >= M) ga1 = M - 1;
  const unsigned short* a0 = A + (size_t)ga0 * K + acol;
  const unsigned short* a1 = A + (size_t)ga1 * K + acol;
  const unsigned short* b0 = B + (size_t)(bn * 128 + arow) * K + acol;
  const unsigned short* b1 = B + (size_t)(bn * 128 + arow + 64) * K + acol;
  unsigned short* lA0 = &lA[t * 8];
  unsigned short* lA1 = &lA[t * 8 + 64 * 32];
  unsigned short* lB0 = &lB[t * 8];
  unsigned short* lB1 = &lB[t * 8 + 64 * 32];

  for (int k0 = 0; k0 < K; k0 += 32) {
    __syncthreads();
    gld_lds16(a0 + k0, lA0);
    gld_lds16(a1 + k0, lA1);
    gld_lds16(b0 + k0, lB0);
    gld_lds16(b1 + k0, lB1);
    __syncthreads();
    short8 af[4], bfr[4];
    for (int i = 0; i < 4; ++i)
      af[i] = *(const short8*)&lA[(wm + i * 16 + (lane & 15)) * 32 + (lane >> 4) * 8];
    for (int j = 0; j < 4; ++j)
      bfr[j] = *(const short8*)&lB[(wn + j * 16 + (lane & 15)) * 32 + (lane >> 4) * 8];
    for (int i = 0; i < 4; ++i)
      for (int j = 0; j < 4; ++j)
        acc[i][j] = __builtin_amdgcn_mfma_f32_16x16x32_bf16(af[i], bfr[j], acc[i][j], 0, 0, 0);
  }

  int rowq = (lane >> 4) * 4;
  for (int j = 0; j < 4; ++j) {
    int col = bn * 128 + wn + j * 16 + (lane & 15);
    float bv = bias[col];
    for (int i = 0; i < 4; ++i) {
      int row0 = bm * 128 + wm + i * 16 + rowq;
      for (int r = 0; r < 4; ++r) {
        int row = row0 + r;
        if (row < M) {
          float v = acc[i][j][r] + bv;
          if (ACT) v = (v > 1e-6f) ? v : 0.0f;
          if (OUT_BF16) ((unsigned short*)Cout)[(size_t)row * N + col] = f2bf(v);
          else          ((float*)Cout)[(size_t)row * N + col] = v;
        }
      }
    }
  }
}

// ------------------------------------------------- one GRU step
// 64 blocks; block j owns h columns [j*16, j*16+16) and gate columns {jc, H+jc, 2H+jc}.
// gh = h_{t-1} @ W_hh^T (K=1024, bf16 MFMA), then gates in fp32, h kept in fp32 master + bf16 copy.
__global__ __launch_bounds__(256) void gru_step(const unsigned short* __restrict__ hb_in,
                                                const float* __restrict__ hf_in,
                                                unsigned short* __restrict__ hb_out,
                                                float* __restrict__ hf_out,
                                                const unsigned short* __restrict__ Whh,
                                                const float* __restrict__ b_hh,
                                                const unsigned short* __restrict__ xw) {
  __shared__ unsigned short lA[64 * 32];   // h tile  [64 batch][32 k]
  __shared__ unsigned short lB[48 * 32];   // W rows  [48 gatecols][32 k]
  int t = threadIdx.x;
  int lane = t & 63;
  int wave = t >> 6;
  int jc = blockIdx.x * 16;
  floatx4 acc[3] = {};

  int arow = t >> 2;          // 0..63
  int acol = (t & 3) * 8;
  const unsigned short* asrc = hb_in + (size_t)arow * H_SZ + acol;
  const unsigned short* bsrc = nullptr;
  if (t < 192) {
    int brow = arow;  // 0..47
    int wrow = (brow >> 4) * H_SZ + jc + (brow & 15);
    bsrc = Whh + (size_t)wrow * H_SZ + acol;
  }
  unsigned short* lAd = &lA[t * 8];
  unsigned short* lBd = &lB[t * 8];

  for (int k0 = 0; k0 < H_SZ; k0 += 32) {
    __syncthreads();
    gld_lds16(asrc + k0, lAd);
    if (t < 192) gld_lds16(bsrc + k0, lBd);
    __syncthreads();
    short8 a = *(const short8*)&lA[(wave * 16 + (lane & 15)) * 32 + (lane >> 4) * 8];
    for (int g = 0; g < 3; ++g) {
      short8 b = *(const short8*)&lB[(g * 16 + (lane & 15)) * 32 + (lane >> 4) * 8];
      acc[g] = __builtin_amdgcn_mfma_f32_16x16x32_bf16(a, b, acc[g], 0, 0, 0);
    }
  }

  int col = jc + (lane & 15);
  float bhr = b_hh[col];
  float bhz = b_hh[H_SZ + col];
  float bhn = b_hh[2 * H_SZ + col];
  int rowq = (lane >> 4) * 4;
  for (int r = 0; r < 4; ++r) {
    int b = wave * 16 + rowq + r;    // batch index 0..63
    float ghr = acc[0][r] + bhr;
    float ghz = acc[1][r] + bhz;
    float ghn = acc[2][r] + bhn;
    float xr = bf2f(xw[(size_t)b * G3 + col]);
    float xz = bf2f(xw[(size_t)b * G3 + H_SZ + col]);
    float xn = bf2f(xw[(size_t)b * G3 + 2 * H_SZ + col]);
    float rr = 1.0f / (1.0f + __expf(-(xr + ghr)));
    float zz = 1.0f / (1.0f + __expf(-(xz + ghz)));
    float nn = tanhf(xn + rr * ghn);
    float ho = hf_in[(size_t)b * H_SZ + col];
    float hnew = (1.0f - zz) * nn + zz * ho;
    hf_out[(size_t)b * H_SZ + col] = hnew;
    hb_out[(size_t)b * H_SZ + col] = f2bf(hnew);
  }
}

// ----------------------------------------------------------------- launch
extern "C" void kernel_launch(void* const* d_in, const int* in_sizes, int n_in,
                              void* d_out, int out_size, void* d_ws, size_t ws_size,
                              hipStream_t stream) {
  const int*   ids   = (const int*)d_in[0];
  const float* W1    = (const float*)d_in[1];
  const float* b1    = (const float*)d_in[2];
  const float* W2    = (const float*)d_in[3];
  const float* b2    = (const float*)d_in[4];
  const float* W_ih  = (const float*)d_in[5];
  const float* b_ih  = (const float*)d_in[6];
  const float* W_hh  = (const float*)d_in[7];
  const float* b_hh  = (const float*)d_in[8];
  const float* W_out = (const float*)d_in[9];
  const float* b_out = (const float*)d_in[10];
  float* out = (float*)d_out;

  uint8_t* wsp = (uint8_t*)d_ws;
  auto alloc = [&](size_t bytes) {
    uint8_t* p = wsp;
    wsp += (bytes + 255) & ~(size_t)255;
    return p;
  };
  unsigned short* W1T   = (unsigned short*)alloc((size_t)V_SZ * EH * 2);      // 32.8 MB
  unsigned short* W2b   = (unsigned short*)alloc((size_t)EO * EH * 2);
  unsigned short* Wihb  = (unsigned short*)alloc((size_t)G3 * EO * 2);
  unsigned short* Whhb  = (unsigned short*)alloc((size_t)G3 * H_SZ * 2);
  unsigned short* Woutb = (unsigned short*)alloc((size_t)O_SZ * H_SZ * 2);
  unsigned short* emb   = (unsigned short*)alloc((size_t)S_LEN * B_SZ * EH * 2);
  unsigned short* x     = (unsigned short*)alloc((size_t)S_LEN * B_SZ * EO * 2);
  unsigned short* xW    = (unsigned short*)alloc((size_t)S_LEN * B_SZ * G3 * 2); // 50 MB
  float* hf0 = (float*)alloc((size_t)B_SZ * H_SZ * 4);
  float* hf1 = (float*)alloc((size_t)B_SZ * H_SZ * 4);
  unsigned short* hb0 = (unsigned short*)alloc((size_t)B_SZ * H_SZ * 2);
  unsigned short* hb1 = (unsigned short*)alloc((size_t)B_SZ * H_SZ * 2);

  // weight converts (fp32 -> bf16)
  {
    int n4;
    n4 = (EO * EH) / 4;
    cvt_bf16<<<dim3((n4 + 255) / 256), 256, 0, stream>>>(W2, W2b, n4);
    n4 = (G3 * EO) / 4;
    cvt_bf16<<<dim3((n4 + 255) / 256), 256, 0, stream>>>(W_ih, Wihb, n4);
    n4 = (G3 * H_SZ) / 4;
    cvt_bf16<<<dim3((n4 + 255) / 256), 256, 0, stream>>>(W_hh, Whhb, n4);
    n4 = (O_SZ * H_SZ) / 4;
    cvt_bf16<<<dim3((n4 + 255) / 256), 256, 0, stream>>>(W_out, Woutb, n4);
  }

  // h0 = 0
  hipMemsetAsync(hf0, 0, (size_t)B_SZ * H_SZ * 4, stream);
  hipMemsetAsync(hb0, 0, (size_t)B_SZ * H_SZ * 2, stream);

  // W1 transpose -> bf16
  transpose_w1_bf16<<<dim3(V_SZ / 64, EH / 64), 256, 0, stream>>>(W1, W1T);

  // embedding gather + b1 + threshold
  gather_emb<<<dim3(S_LEN * B_SZ / 4), 256, 0, stream>>>(ids, W1T, b1, emb);

  // x = thresh(emb @ W2^T + b2)   [8192, 512]
  gemm_bt<1, 1><<<dim3(EO / 128, S_LEN * B_SZ / 128), 256, 0, stream>>>(
      emb, W2b, b2, x, S_LEN * B_SZ, EO, EH);

  // xW = x @ W_ih^T + b_ih        [8192, 3072]
  gemm_bt<0, 1><<<dim3(G3 / 128, S_LEN * B_SZ / 128), 256, 0, stream>>>(
      x, Wihb, b_ih, xW, S_LEN * B_SZ, G3, EO);

  // GRU recurrence, one launch per step, double-buffered h
  for (int s = 0; s < S_LEN; ++s) {
    const unsigned short* hbi = (s & 1) ? hb1 : hb0;
    const float*          hfi = (s & 1) ? hf1 : hf0;
    unsigned short*       hbo = (s & 1) ? hb0 : hb1;
    float*                hfo = (s & 1) ? hf0 : hf1;
    gru_step<<<dim3(H_SZ / 16), 256, 0, stream>>>(
        hbi, hfi, hbo, hfo, Whhb, b_hh, xW + (size_t)s * B_SZ * G3);
  }
  // 128 steps: final h lives in buffer 0 (last step s=127 writes hb0/hf0)

  // out = h @ W_out^T + b_out     [64, 1024] fp32
  gemm_bt<0, 0><<<dim3(O_SZ / 128, 1), 256, 0, stream>>>(
      hb0, Woutb, b_out, out, B_SZ, O_SZ, H_SZ);
}